// Round 4
// baseline (366.505 us; speedup 1.0000x reference)
//
#include <hip/hip_runtime.h>
#include <hip/hip_bf16.h>

typedef __bf16 bf16x8 __attribute__((ext_vector_type(8)));
typedef float  f32x16 __attribute__((ext_vector_type(16)));
typedef float  f32x4  __attribute__((ext_vector_type(4)));

#define UF_D 256
#define MAP_M 64
#define B_DIM 32
#define U_DIM 512
#define S_DIM 4096

// ---------------------------------------------------------------------------
// Kernel 1 (proj): proj[16384][64] = relu(ufeat @ (g*V/||V||/8)^T + b/8), bf16.
// - Each block redundantly computes ||V||_F^2 (64 KB, L2-resident) -> no
//   separate prep kernel, no serializing 1-block launch.
// - 1024 blocks x 4 waves, 16x16x32 MFMA: block = 16 ufeat rows shared by all
//   4 waves (each wave one 16-col slice of w) -> L1 reuse, 4 waves/SIMD.
// ---------------------------------------------------------------------------
__global__ __launch_bounds__(256) void proj_kernel(
    const float* __restrict__ ufeat,    // [16384, 256] f32
    const float* __restrict__ v_w,      // [64, 256] f32
    const float* __restrict__ g,        // [1]
    const float* __restrict__ b,        // [64]
    __bf16* __restrict__ proj)          // [16384, 64] bf16
{
    const int t = threadIdx.x;

    // block-redundant Frobenius norm of V (16384 f32 = 64 KB)
    __shared__ float red[256];
    {
        const f32x4* v4 = (const f32x4*)v_w;   // 4096 vec4
        float ss = 0.f;
        for (int i = t; i < 4096; i += 256) {
            f32x4 v = v4[i];
            ss += v.x * v.x + v.y * v.y + v.z * v.z + v.w * v.w;
        }
        red[t] = ss;
        __syncthreads();
        for (int s = 128; s > 0; s >>= 1) {
            if (t < s) red[t] += red[t + s];
            __syncthreads();
        }
    }
    const float scale = g[0] / (sqrtf(red[0]) * 8.0f);

    const int wave = t >> 6;
    const int lane = t & 63;
    const int r  = lane & 15;           // A row / B col within fragment
    const int kq = lane >> 4;           // k-group 0..3 -> k offset kq*8
    const int row0 = blockIdx.x * 16;
    const int col0 = wave * 16;

    f32x4 acc = {};
    const float* ap = ufeat + (size_t)(row0 + r) * UF_D + kq * 8;
    const float* wp = v_w   + (size_t)(col0 + r) * UF_D + kq * 8;

#pragma unroll
    for (int k = 0; k < UF_D; k += 32) {
        f32x4 a0 = *(const f32x4*)(ap + k);
        f32x4 a1 = *(const f32x4*)(ap + k + 4);
        f32x4 w0 = *(const f32x4*)(wp + k);
        f32x4 w1 = *(const f32x4*)(wp + k + 4);
        bf16x8 af, wf;
        af[0] = (__bf16)a0.x; af[1] = (__bf16)a0.y;
        af[2] = (__bf16)a0.z; af[3] = (__bf16)a0.w;
        af[4] = (__bf16)a1.x; af[5] = (__bf16)a1.y;
        af[6] = (__bf16)a1.z; af[7] = (__bf16)a1.w;
        wf[0] = (__bf16)(w0.x * scale); wf[1] = (__bf16)(w0.y * scale);
        wf[2] = (__bf16)(w0.z * scale); wf[3] = (__bf16)(w0.w * scale);
        wf[4] = (__bf16)(w1.x * scale); wf[5] = (__bf16)(w1.y * scale);
        wf[6] = (__bf16)(w1.z * scale); wf[7] = (__bf16)(w1.w * scale);
        acc = __builtin_amdgcn_mfma_f32_16x16x32_bf16(af, wf, acc, 0, 0, 0);
    }

    // C/D layout (16x16, verified m89): col = lane&15, row = (lane>>4)*4 + j
#pragma unroll
    for (int j = 0; j < 4; ++j) {
        const int row = row0 + kq * 4 + j;
        const int col = col0 + r;
        float v = acc[j] + b[col] * 0.125f;
        proj[(size_t)row * MAP_M + col] = (__bf16)fmaxf(v, 0.f);
    }
}

// ---------------------------------------------------------------------------
// Kernel 2 (logit): per batch: out[512][4096] = proj_b @ map_b^T (scale
// pre-folded into proj). 128x128 tile, 4 waves 2x2, each 64x64 = 2x2 frags of
// 32x32x16 MFMA. mapfeat read as f32 directly (no conversion pass: 32 MB read
// once via L2 beats 48 MB conv + 16 MB read), converted in-loop (hides under
// store BW). Bijective XCD swizzle: the 4 u-blocks of an s-tile + their map
// rows stay on one XCD L2. Nontemporal stores keep the 268 MB output stream
// from evicting proj/map from L2.
// ---------------------------------------------------------------------------
__global__ __launch_bounds__(256) void logit_kernel(
    const __bf16* __restrict__ proj,    // [32, 512, 64] bf16
    const float* __restrict__ map,      // [32, 4096, 64] f32
    float* __restrict__ out)            // [32, 512, 4096] f32
{
    const int vid = (blockIdx.x & 7) * 512 + (blockIdx.x >> 3);  // XCD swizzle
    const int ut = vid & 3;
    const int st = (vid >> 2) & 31;
    const int b  = vid >> 7;

    const int wave = threadIdx.x >> 6;
    const int lane = threadIdx.x & 63;
    const int wr = wave >> 1, wc = wave & 1;
    const int r  = lane & 31;
    const int kh = lane >> 5;

    const int u0 = ut * 128 + wr * 64;
    const int s0 = st * 128 + wc * 64;

    const __bf16* A  = proj + (size_t)b * U_DIM * MAP_M;
    const float*  Bm = map  + (size_t)b * S_DIM * MAP_M;

    f32x16 acc00 = {}, acc01 = {}, acc10 = {}, acc11 = {};

    const __bf16* a0p = A  + (size_t)(u0 + r)      * MAP_M + kh * 8;
    const __bf16* a1p = A  + (size_t)(u0 + 32 + r) * MAP_M + kh * 8;
    const float*  b0p = Bm + (size_t)(s0 + r)      * MAP_M + kh * 8;
    const float*  b1p = Bm + (size_t)(s0 + 32 + r) * MAP_M + kh * 8;

#pragma unroll
    for (int k = 0; k < MAP_M; k += 16) {
        bf16x8 a0 = *(const bf16x8*)(a0p + k);
        bf16x8 a1 = *(const bf16x8*)(a1p + k);
        f32x4 q0 = *(const f32x4*)(b0p + k);
        f32x4 q1 = *(const f32x4*)(b0p + k + 4);
        f32x4 q2 = *(const f32x4*)(b1p + k);
        f32x4 q3 = *(const f32x4*)(b1p + k + 4);
        bf16x8 f0, f1;
        f0[0] = (__bf16)q0.x; f0[1] = (__bf16)q0.y;
        f0[2] = (__bf16)q0.z; f0[3] = (__bf16)q0.w;
        f0[4] = (__bf16)q1.x; f0[5] = (__bf16)q1.y;
        f0[6] = (__bf16)q1.z; f0[7] = (__bf16)q1.w;
        f1[0] = (__bf16)q2.x; f1[1] = (__bf16)q2.y;
        f1[2] = (__bf16)q2.z; f1[3] = (__bf16)q2.w;
        f1[4] = (__bf16)q3.x; f1[5] = (__bf16)q3.y;
        f1[6] = (__bf16)q3.z; f1[7] = (__bf16)q3.w;
        acc00 = __builtin_amdgcn_mfma_f32_32x32x16_bf16(a0, f0, acc00, 0, 0, 0);
        acc01 = __builtin_amdgcn_mfma_f32_32x32x16_bf16(a0, f1, acc01, 0, 0, 0);
        acc10 = __builtin_amdgcn_mfma_f32_32x32x16_bf16(a1, f0, acc10, 0, 0, 0);
        acc11 = __builtin_amdgcn_mfma_f32_32x32x16_bf16(a1, f1, acc11, 0, 0, 0);
    }

    float* O = out + (size_t)b * U_DIM * S_DIM;
#pragma unroll
    for (int j = 0; j < 16; ++j) {
        const int rl = (j & 3) + 8 * (j >> 2) + 4 * kh;
        const size_t row0 = u0 + rl;
        const size_t row1 = u0 + 32 + rl;
        __builtin_nontemporal_store(acc00[j], &O[row0 * S_DIM + s0 + r]);
        __builtin_nontemporal_store(acc01[j], &O[row0 * S_DIM + s0 + 32 + r]);
        __builtin_nontemporal_store(acc10[j], &O[row1 * S_DIM + s0 + r]);
        __builtin_nontemporal_store(acc11[j], &O[row1 * S_DIM + s0 + 32 + r]);
    }
}

// ---------------------------------------------------------------------------
extern "C" void kernel_launch(void* const* d_in, const int* in_sizes, int n_in,
                              void* d_out, int out_size, void* d_ws, size_t ws_size,
                              hipStream_t stream) {
    const float* ufeat   = (const float*)d_in[0];   // [32,512,256]
    const float* mapfeat = (const float*)d_in[1];   // [32,4096,64]
    const float* v_w     = (const float*)d_in[2];   // [64,256]
    const float* g       = (const float*)d_in[3];   // [1]
    const float* b       = (const float*)d_in[4];   // [64]
    float* out = (float*)d_out;                     // [32,512,4096]

    __bf16* proj = (__bf16*)d_ws;                   // 2 MB scratch

    proj_kernel<<<1024, 256, 0, stream>>>(ufeat, v_w, g, b, proj);
    logit_kernel<<<B_DIM * 32 * 4, 256, 0, stream>>>(proj, mapfeat, out);
}

// Round 6
// 326.523 us; speedup vs baseline: 1.1224x; 1.1224x over previous
//
#include <hip/hip_runtime.h>
#include <hip/hip_bf16.h>

typedef __bf16 bf16x8 __attribute__((ext_vector_type(8)));
typedef float  f32x16 __attribute__((ext_vector_type(16)));
typedef float  f32x4  __attribute__((ext_vector_type(4)));

#define UF_D 256
#define MAP_M 64
#define B_DIM 32
#define U_DIM 512
#define S_DIM 4096

// ---------------------------------------------------------------------------
// Kernel 1: block 0 -> weight-norm scale (g/||V||/8 folded into w and b),
// emit w_bf16[64][256], b_s = b/8. Blocks 1..255 -> convert mapfeat f32->bf16
// (32 MB -> 16 MB): logit then reads half the bytes with zero in-loop cvts.
// map_bf16 stored with PLAIN stores (leave in L2 for logit); f32 reads NT.
// ---------------------------------------------------------------------------
__global__ __launch_bounds__(256) void prep_conv_kernel(
    const float* __restrict__ v_w, const float* __restrict__ g,
    const float* __restrict__ b, const float* __restrict__ mapfeat,
    __bf16* __restrict__ w_bf16, float* __restrict__ b_s,
    __bf16* __restrict__ map_bf16)
{
    const int t = threadIdx.x;
    if (blockIdx.x == 0) {
        __shared__ float red[256];
        const f32x4* v4 = (const f32x4*)v_w;   // 16384 f32 = 4096 vec4
        float ss = 0.f;
        for (int i = t; i < 4096; i += 256) {
            f32x4 v = v4[i];
            ss += v.x * v.x + v.y * v.y + v.z * v.z + v.w * v.w;
        }
        red[t] = ss;
        __syncthreads();
        for (int s = 128; s > 0; s >>= 1) {
            if (t < s) red[t] += red[t + s];
            __syncthreads();
        }
        const float scale = g[0] / (sqrtf(red[0]) * 8.0f);
        for (int i = t; i < 4096; i += 256) {
            f32x4 v = v4[i];
            w_bf16[4 * i + 0] = (__bf16)(v.x * scale);
            w_bf16[4 * i + 1] = (__bf16)(v.y * scale);
            w_bf16[4 * i + 2] = (__bf16)(v.z * scale);
            w_bf16[4 * i + 3] = (__bf16)(v.w * scale);
        }
        if (t < MAP_M) b_s[t] = b[t] * 0.125f;
    } else {
        const int NC = (B_DIM * S_DIM * MAP_M) / 8;   // 1,048,576 chunks of 8
        const f32x4* m4 = (const f32x4*)mapfeat;
        bf16x8* o8 = (bf16x8*)map_bf16;
        for (int c = (blockIdx.x - 1) * 256 + t; c < NC; c += 255 * 256) {
            f32x4 q0 = __builtin_nontemporal_load(&m4[2 * c]);
            f32x4 q1 = __builtin_nontemporal_load(&m4[2 * c + 1]);
            bf16x8 o;
            o[0] = (__bf16)q0.x; o[1] = (__bf16)q0.y;
            o[2] = (__bf16)q0.z; o[3] = (__bf16)q0.w;
            o[4] = (__bf16)q1.x; o[5] = (__bf16)q1.y;
            o[6] = (__bf16)q1.z; o[7] = (__bf16)q1.w;
            o8[c] = o;
        }
    }
}

// ---------------------------------------------------------------------------
// Kernel 2: proj[16384][64] = relu(ufeat @ w^T + b/8) in bf16 (R3 version).
// 256 blocks x 64 rows. 4 waves: (wr,wc) 2x2, each one 32x32 fragment, K=256.
// ---------------------------------------------------------------------------
__global__ __launch_bounds__(256) void proj_kernel(
    const float* __restrict__ ufeat,    // [16384, 256] f32
    const __bf16* __restrict__ w,       // [64, 256] bf16 (pre-scaled)
    const float* __restrict__ b_s,      // [64] f32 (b/8)
    __bf16* __restrict__ proj)          // [16384, 64] bf16
{
    const int wave = threadIdx.x >> 6;
    const int lane = threadIdx.x & 63;
    const int r  = lane & 31;
    const int kh = lane >> 5;
    const int wr = wave >> 1, wc = wave & 1;
    const int row0 = blockIdx.x * 64 + wr * 32;
    const int col0 = wc * 32;

    f32x16 acc = {};
    const float*  ap = ufeat + (size_t)(row0 + r) * UF_D + kh * 8;
    const __bf16* wp = w + (col0 + r) * UF_D + kh * 8;

#pragma unroll
    for (int k = 0; k < UF_D; k += 16) {
        f32x4 a01 = *(const f32x4*)(ap + k);
        f32x4 a23 = *(const f32x4*)(ap + k + 4);
        bf16x8 af;
        af[0] = (__bf16)a01.x; af[1] = (__bf16)a01.y;
        af[2] = (__bf16)a01.z; af[3] = (__bf16)a01.w;
        af[4] = (__bf16)a23.x; af[5] = (__bf16)a23.y;
        af[6] = (__bf16)a23.z; af[7] = (__bf16)a23.w;
        bf16x8 wf = *(const bf16x8*)(wp + k);
        acc = __builtin_amdgcn_mfma_f32_32x32x16_bf16(af, wf, acc, 0, 0, 0);
    }

    // C/D layout: col = lane&31, row = (j&3)+8*(j>>2)+4*(lane>>5)
#pragma unroll
    for (int j = 0; j < 16; ++j) {
        const int rl = (j & 3) + 8 * (j >> 2) + 4 * kh;
        const size_t row = row0 + rl;
        const int col = col0 + r;
        float v = acc[j] + b_s[col];
        proj[row * MAP_M + col] = (__bf16)fmaxf(v, 0.f);
    }
}

// ---------------------------------------------------------------------------
// Kernel 3 (logit): per batch: out[512][4096] = proj_b @ map_b^T, bf16 in.
// Tile = 32u x 512s (vs 128x128): each output row gets 2 KB contiguous per
// tile -> better DRAM page locality on the 268 MB write stream. 4 waves: one
// 32x128 slice each (1 A-frag shared by 4 B-frags, K=64 -> 16 MFMA).
// Grid (b=32, st=8, ut=16); bijective XCD swizzle puts all 16 ut-blocks of a
// (b,st) on one XCD consecutively -> map s-tile (64 KB) L2-hot.
// NT stores keep the output stream from evicting L2.
// ---------------------------------------------------------------------------
__global__ __launch_bounds__(256) void logit_kernel(
    const __bf16* __restrict__ proj,    // [32, 512, 64] bf16
    const __bf16* __restrict__ map,     // [32, 4096, 64] bf16
    float* __restrict__ out)            // [32, 512, 4096] f32
{
    const int vid = (blockIdx.x & 7) * 512 + (blockIdx.x >> 3);  // XCD swizzle
    const int ut = vid & 15;            // 16 u-tiles of 32 rows
    const int st = (vid >> 4) & 7;      // 8 s-tiles of 512 cols
    const int b  = vid >> 7;            // 32 batches

    const int wave = threadIdx.x >> 6;
    const int lane = threadIdx.x & 63;
    const int r  = lane & 31;
    const int kh = lane >> 5;

    const int u0 = ut * 32;
    const int s0 = st * 512 + wave * 128;

    const __bf16* A  = proj + (size_t)b * U_DIM * MAP_M;
    const __bf16* Bm = map  + (size_t)b * S_DIM * MAP_M;

    f32x16 acc0 = {}, acc1 = {}, acc2 = {}, acc3 = {};

    const __bf16* ap  = A  + (size_t)(u0 + r) * MAP_M + kh * 8;
    const __bf16* bp0 = Bm + (size_t)(s0 +   0 + r) * MAP_M + kh * 8;
    const __bf16* bp1 = Bm + (size_t)(s0 +  32 + r) * MAP_M + kh * 8;
    const __bf16* bp2 = Bm + (size_t)(s0 +  64 + r) * MAP_M + kh * 8;
    const __bf16* bp3 = Bm + (size_t)(s0 +  96 + r) * MAP_M + kh * 8;

#pragma unroll
    for (int k = 0; k < MAP_M; k += 16) {
        bf16x8 a  = *(const bf16x8*)(ap  + k);
        bf16x8 f0 = *(const bf16x8*)(bp0 + k);
        bf16x8 f1 = *(const bf16x8*)(bp1 + k);
        bf16x8 f2 = *(const bf16x8*)(bp2 + k);
        bf16x8 f3 = *(const bf16x8*)(bp3 + k);
        acc0 = __builtin_amdgcn_mfma_f32_32x32x16_bf16(a, f0, acc0, 0, 0, 0);
        acc1 = __builtin_amdgcn_mfma_f32_32x32x16_bf16(a, f1, acc1, 0, 0, 0);
        acc2 = __builtin_amdgcn_mfma_f32_32x32x16_bf16(a, f2, acc2, 0, 0, 0);
        acc3 = __builtin_amdgcn_mfma_f32_32x32x16_bf16(a, f3, acc3, 0, 0, 0);
    }

    float* O = out + (size_t)b * U_DIM * S_DIM;
#pragma unroll
    for (int j = 0; j < 16; ++j) {
        const int rl = (j & 3) + 8 * (j >> 2) + 4 * kh;
        const size_t row = u0 + rl;
        float* orow = O + row * S_DIM + s0 + r;
        __builtin_nontemporal_store(acc0[j], orow);
        __builtin_nontemporal_store(acc1[j], orow + 32);
        __builtin_nontemporal_store(acc2[j], orow + 64);
        __builtin_nontemporal_store(acc3[j], orow + 96);
    }
}

// ---------------------------------------------------------------------------
extern "C" void kernel_launch(void* const* d_in, const int* in_sizes, int n_in,
                              void* d_out, int out_size, void* d_ws, size_t ws_size,
                              hipStream_t stream) {
    const float* ufeat   = (const float*)d_in[0];   // [32,512,256]
    const float* mapfeat = (const float*)d_in[1];   // [32,4096,64]
    const float* v_w     = (const float*)d_in[2];   // [64,256]
    const float* g       = (const float*)d_in[3];   // [1]
    const float* b       = (const float*)d_in[4];   // [64]
    float* out = (float*)d_out;                     // [32,512,4096]

    __bf16* w_bf16   = (__bf16*)d_ws;                               // 32 KB
    float*  b_s      = (float*)((char*)d_ws + 32768);               // 256 B
    __bf16* proj     = (__bf16*)((char*)d_ws + 65536);              // 2 MB
    __bf16* map_bf16 = (__bf16*)((char*)d_ws + 65536 + 2097152);    // 16 MB

    prep_conv_kernel<<<256, 256, 0, stream>>>(v_w, g, b, mapfeat, w_bf16, b_s, map_bf16);
    proj_kernel<<<256, 256, 0, stream>>>(ufeat, w_bf16, b_s, proj);
    logit_kernel<<<B_DIM * 8 * 16, 256, 0, stream>>>(proj, map_bf16, out);
}